// Round 5
// baseline (608.889 us; speedup 1.0000x reference)
//
#include <hip/hip_runtime.h>
#include <hip/hip_bf16.h>
#include <cstdint>

// GroupFNO1d on MI355X. Rows = B*E = 32768.
// Algebra: spectral (64 kept rFFT modes) == analysis GEMM (128 cos/-sin rows) +
// per-(e,k) complex mix + synthesis folded into next weight (K 1024->1152).
// NEW round 5: spectral-1 folded INTO GEMM-1 (no activation in between):
//   X = (A0@p_w^T+p_b)@Fb^T = A0@(Fb@p_w)^T + const  -> GEMM-1 B-panel = [p_w | G],
//   mix applied in GEMM-1's epilogue. Grid half of A0 is row-constant -> folded
//   into bias; GEMM-1 K=512. Layer-2 spectral can't fold (swish) -> gemm_mix kept.
// GEMM loop = round-4 proven structure (swizzled LDS, 0 bank conflicts), untouched.

typedef __bf16 bf16;
typedef __attribute__((ext_vector_type(8))) __bf16 bf16x8;
typedef __attribute__((ext_vector_type(4))) __bf16 bf16x4;
typedef __attribute__((ext_vector_type(4))) float f32x4;

#define N_ROWS 32768

__device__ __forceinline__ void gl_lds16(const void* g, void* l) {
    __builtin_amdgcn_global_load_lds(
        (const __attribute__((address_space(1))) void*)g,
        (__attribute__((address_space(3))) void*)l,
        16, 0, 0);
}

__device__ __forceinline__ float swishf(float v) {
    return v / (1.f + __expf(-v));
}

// ---------------- setup kernels ----------------

// cmix[e*64+k] = g_k*(lam_k*com_c[k] + (1-lam_k)*(codes@code)[e,k]), g_0=1/1024 else 2/1024
__global__ __launch_bounds__(256) void build_cmix(const float* __restrict__ codes,
                                                  const float* __restrict__ com,
                                                  const float* __restrict__ code,
                                                  const float* __restrict__ filt,
                                                  float2* __restrict__ cmix) {
    int t = blockIdx.x * 256 + threadIdx.x;
    if (t >= 16 * 64) return;
    int e = t >> 6, m = t & 63;
    float er = 0.f, ei = 0.f;
    for (int c = 0; c < 64; ++c) {
        float cd = codes[e * 64 + c];
        er += cd * code[(c * 64 + m) * 2 + 0];
        ei += cd * code[(c * 64 + m) * 2 + 1];
    }
    float f = filt[m];
    float lam = fminf(fmaxf((f + 3.f) * (1.f / 6.f), 0.f), 1.f);
    float cr = lam * com[m * 2 + 0] + (1.f - lam) * er;
    float ci = lam * com[m * 2 + 1] + (1.f - lam) * ei;
    float g = (m == 0) ? (1.f / 1024.f) : (2.f / 1024.f);
    cmix[t] = make_float2(g * cr, g * ci);
}

// Fb (128 x 1024): row 2k = cos(2*pi*k*w/1024), row 2k+1 = -sin. f32 + bf16 copies.
__global__ __launch_bounds__(256) void build_fb2(float* __restrict__ Fb32,
                                                 bf16* __restrict__ Fbb) {
    int t = blockIdx.x * 256 + threadIdx.x;   // 131072
    int rr = t >> 10, s = t & 1023;
    int k = rr >> 1;
    int ph = (k * s) & 1023;
    float ang = (float)ph * 6.1359231515425649e-3f;  // 2*pi/1024
    float v = (rr & 1) ? -sinf(ang) : cosf(ang);
    Fb32[t] = v;
    Fbb[t] = (bf16)v;
}

// Bcat (1024 x 1152): cols<1024 = w[j][c]; col 1024+2k = cos(2*pi*k*j/1024), +2k+1 = -sin
__global__ __launch_bounds__(256) void build_bcat(const float* __restrict__ w,
                                                  bf16* __restrict__ out) {
    int t = blockIdx.x * 256 + threadIdx.x;
    if (t >= 1024 * 1152) return;
    int j = t / 1152, c = t % 1152;
    float v;
    if (c < 1024) {
        v = w[j * 1024 + c];
    } else {
        int cc = c - 1024, k = cc >> 1;
        int ph = (k * j) & 1023;
        float ang = (float)ph * 6.1359231515425649e-3f;
        v = (cc & 1) ? -sinf(ang) : cosf(ang);
    }
    out[t] = (bf16)v;
}

// G32[k2][c] = sum_w Fb32[k2][w] * p_w[w][c], c<512. grid (2 cslice, 32 k2grp), 4 acc/thr.
__global__ __launch_bounds__(256) void build_g(const float* __restrict__ Fb32,
                                               const float* __restrict__ p_w,
                                               float* __restrict__ G32) {
    int c = blockIdx.x * 256 + threadIdx.x;
    int k0 = blockIdx.y * 4;
    float a0 = 0.f, a1 = 0.f, a2 = 0.f, a3 = 0.f;
    #pragma unroll 4
    for (int w = 0; w < 1024; ++w) {
        float pv = p_w[(size_t)w * 1024 + c];
        a0 += Fb32[(k0 + 0) * 1024 + w] * pv;
        a1 += Fb32[(k0 + 1) * 1024 + w] * pv;
        a2 += Fb32[(k0 + 2) * 1024 + w] * pv;
        a3 += Fb32[(k0 + 3) * 1024 + w] * pv;
    }
    G32[(k0 + 0) * 512 + c] = a0;
    G32[(k0 + 1) * 512 + c] = a1;
    G32[(k0 + 2) * 512 + c] = a2;
    G32[(k0 + 3) * 512 + c] = a3;
}

// bias1[w] = p_b[w] + sum_s (s/511)*p_w[w][512+s], w<1024
__global__ __launch_bounds__(256) void build_bias1a(const float* __restrict__ p_w,
                                                    const float* __restrict__ p_b,
                                                    float* __restrict__ bias1) {
    int w = blockIdx.x * 256 + threadIdx.x;
    if (w >= 1024) return;
    float s = 0.f;
    for (int i = 0; i < 512; ++i)
        s += ((float)i * (1.f / 511.f)) * p_w[(size_t)w * 1024 + 512 + i];
    bias1[w] = p_b[w] + s;
}

// bias1[1024+k2] = sum_w Fb32[k2][w]*bias1[w]; zero pad 1152..1279. AFTER bias1a.
__global__ __launch_bounds__(128) void build_bias1b(const float* __restrict__ Fb32,
                                                    float* __restrict__ bias1) {
    int k2 = threadIdx.x;   // 128
    float s = 0.f;
    for (int w = 0; w < 1024; ++w) s += Fb32[k2 * 1024 + w] * bias1[w];
    bias1[1024 + k2] = s;
    bias1[1152 + k2] = 0.f;
}

// WP (1280 x 512 bf16): rows<1024 = p_w[r][c]; 1024..1151 = G32; >=1152 = 0
__global__ __launch_bounds__(256) void build_wp(const float* __restrict__ p_w,
                                                const float* __restrict__ G32,
                                                bf16* __restrict__ WP) {
    int t = blockIdx.x * 256 + threadIdx.x;   // 655360
    if (t >= 1280 * 512) return;
    int r = t >> 9, c = t & 511;
    float v = (r < 1024) ? p_w[(size_t)r * 1024 + c]
            : (r < 1152) ? G32[(r - 1024) * 512 + c] : 0.f;
    WP[t] = (bf16)v;
}

// A0[n][c] = bf16(x[n*512+c])  (x is row-major (B, E*S) == flat by n)
__global__ __launch_bounds__(256) void convert_x(const float* __restrict__ x,
                                                 bf16* __restrict__ A0) {
    int t = blockIdx.x * 256 + threadIdx.x;   // rows*64, 8 elems each
    const float4* xp = (const float4*)(x + (size_t)t * 8);
    float4 a = xp[0], b = xp[1];
    bf16x8 o;
    o[0] = (bf16)a.x; o[1] = (bf16)a.y; o[2] = (bf16)a.z; o[3] = (bf16)a.w;
    o[4] = (bf16)b.x; o[5] = (bf16)b.y; o[6] = (bf16)b.z; o[7] = (bf16)b.w;
    *(bf16x8*)(A0 + (size_t)t * 8) = o;
}

// ---------------- big GEMM: 256x256 tile, BK=64, T2 swizzle (round-4 proven) -------
// C = A @ Bt^T + bias (+swish | +mix tail cols), bf16 out. 512 thr = 8 waves (2Mx4N),
// per-wave 128x64 C. LDS [2][256*64] per matrix (128KB). Swizzle both-sides (rule 21).
// HASMIX: cols>=1024 get complex mix via shfl_xor pair (cmix[(row&15)*64+k]);
// stores guarded col<ncols.
template<int ACT, int HASMIX>
__global__ __launch_bounds__(512, 2)
void gemm256(const bf16* __restrict__ A, int lda,
             const bf16* __restrict__ Bt, int ldb,
             const float* __restrict__ bias,
             bf16* __restrict__ Cout, int ldc,
             const float2* __restrict__ cmix, int ncols,
             int K) {
    __shared__ bf16 sA[2][256 * 64];
    __shared__ bf16 sB[2][256 * 64];
    const int tid = threadIdx.x;
    const int wave = tid >> 6, lane = tid & 63;
    const int wm = wave >> 2, wn = wave & 3;
    const int rowA0 = blockIdx.x * 256;
    const int rowB0 = blockIdx.y * 256;

    f32x4 acc[8][4];
    #pragma unroll
    for (int m = 0; m < 8; ++m)
        #pragma unroll
        for (int n = 0; n < 4; ++n)
            acc[m][n] = f32x4{0.f, 0.f, 0.f, 0.f};

    const int srq = lane >> 3;                 // row within 8-row group
    const int ssl = (lane & 7) ^ srq;          // inverse-swizzled 16B col slot
    const bf16* gA = A + (size_t)(rowA0 + wave * 8 + srq) * lda + ssl * 8;
    const bf16* gB = Bt + (size_t)(rowB0 + wave * 8 + srq) * ldb + ssl * 8;

    const int NT = K / 64;
    auto STAGE = [&](int t) {
        const int slot = t & 1;
        const size_t ko = (size_t)t * 64;
        #pragma unroll
        for (int j = 0; j < 4; ++j) {
            gl_lds16(gA + (size_t)j * 64 * lda + ko, &sA[slot][(j * 64 + wave * 8) * 64]);
            gl_lds16(gB + (size_t)j * 64 * ldb + ko, &sB[slot][(j * 64 + wave * 8) * 64]);
        }
    };

    STAGE(0);

    const int p = lane & 15, q = lane >> 4;
    const int axr = (p & 7) << 4;              // read-side byte XOR

    for (int t = 0; t < NT; ++t) {
        asm volatile("s_waitcnt vmcnt(0)" ::: "memory");
        __builtin_amdgcn_s_barrier();
        __builtin_amdgcn_sched_barrier(0);
        if (t + 1 < NT) STAGE(t + 1);
        const char* sa = (const char*)sA[t & 1];
        const char* sb = (const char*)sB[t & 1];
        #pragma unroll
        for (int kk = 0; kk < 64; kk += 32) {
            bf16x8 af[8], bfr[4];
            #pragma unroll
            for (int m = 0; m < 8; ++m) {
                int off = (((wm * 128 + m * 16 + p) * 64 + kk + q * 8) * 2) ^ axr;
                af[m] = *(const bf16x8*)(sa + off);
            }
            #pragma unroll
            for (int n = 0; n < 4; ++n) {
                int off = (((wn * 64 + n * 16 + p) * 64 + kk + q * 8) * 2) ^ axr;
                bfr[n] = *(const bf16x8*)(sb + off);
            }
            asm volatile("s_waitcnt lgkmcnt(0)" ::: "memory");
            __builtin_amdgcn_sched_barrier(0);
            __builtin_amdgcn_s_setprio(1);
            #pragma unroll
            for (int m = 0; m < 8; ++m)
                #pragma unroll
                for (int n = 0; n < 4; ++n)
                    acc[m][n] = __builtin_amdgcn_mfma_f32_16x16x32_bf16(af[m], bfr[n], acc[m][n], 0, 0, 0);
            __builtin_amdgcn_s_setprio(0);
            __builtin_amdgcn_sched_barrier(0);
        }
    }

    const int rowb = rowA0 + wm * 128;
    const int colb = rowB0 + wn * 64;
    #pragma unroll
    for (int m = 0; m < 8; ++m) {
        #pragma unroll
        for (int n = 0; n < 4; ++n) {
            int col = colb + n * 16 + p;
            float bv = bias ? bias[col] : 0.f;
            #pragma unroll
            for (int r = 0; r < 4; ++r) {
                int row = rowb + m * 16 + q * 4 + r;
                float v = acc[m][n][r] + bv;
                if (HASMIX) {
                    float pp = __shfl_xor(v, 1);       // partner col (uniform exec)
                    if (col >= 1024) {
                        int k = (col - 1024) >> 1;
                        float2 c = cmix[(row & 15) * 64 + k];
                        v = v * c.x + (((p & 1) == 0) ? -pp * c.y : pp * c.y);
                    }
                    if (col < ncols) Cout[(size_t)row * ldc + col] = (bf16)v;
                } else {
                    if (ACT) v = swishf(v);
                    Cout[(size_t)row * ldc + col] = (bf16)v;
                }
            }
        }
    }
}

// ---------------- 128^2 GEMM for the layer-2 analysis+mix step ----------------
__global__ __launch_bounds__(256)
void gemm_mix(const bf16* __restrict__ A, int lda,
              const bf16* __restrict__ Bt, int ldb,
              void* __restrict__ Cout, int ldc,
              const float2* __restrict__ cmix,
              int K) {
    __shared__ bf16 sA[128 * 64];
    __shared__ bf16 sB[128 * 64];
    const int tid = threadIdx.x;
    const int wave = tid >> 6;
    const int lane = tid & 63;
    const int wm = wave >> 1, wn = wave & 1;
    const int rowA0 = blockIdx.x * 128;

    f32x4 acc[4][4];
    #pragma unroll
    for (int m = 0; m < 4; ++m)
        #pragma unroll
        for (int n = 0; n < 4; ++n)
            acc[m][n] = f32x4{0.f, 0.f, 0.f, 0.f};

    const int srow = wave * 32 + (lane >> 3);
    const int scol = (lane & 7) * 8;
    const bf16* gA = A + (size_t)(rowA0 + srow) * lda + scol;
    const bf16* gB = Bt + (size_t)srow * ldb + scol;
    bf16* lA = &sA[(wave * 32) * 64];
    bf16* lB = &sB[(wave * 32) * 64];

    for (int k0 = 0; k0 < K; k0 += 64) {
        __syncthreads();
        #pragma unroll
        for (int i = 0; i < 4; ++i) {
            gl_lds16(gA + (size_t)i * 8 * lda + k0, lA + i * 8 * 64);
            gl_lds16(gB + (size_t)i * 8 * ldb + k0, lB + i * 8 * 64);
        }
        __syncthreads();
        #pragma unroll
        for (int kk = 0; kk < 64; kk += 32) {
            bf16x8 af[4], bfr[4];
            #pragma unroll
            for (int m = 0; m < 4; ++m)
                af[m] = *(const bf16x8*)&sA[(wm * 64 + m * 16 + (lane & 15)) * 64 + kk + ((lane >> 4) * 8)];
            #pragma unroll
            for (int n = 0; n < 4; ++n)
                bfr[n] = *(const bf16x8*)&sB[(wn * 64 + n * 16 + (lane & 15)) * 64 + kk + ((lane >> 4) * 8)];
            #pragma unroll
            for (int m = 0; m < 4; ++m)
                #pragma unroll
                for (int n = 0; n < 4; ++n)
                    acc[m][n] = __builtin_amdgcn_mfma_f32_16x16x32_bf16(af[m], bfr[n], acc[m][n], 0, 0, 0);
        }
    }

    const int rowb = rowA0 + wm * 64;
    #pragma unroll
    for (int m = 0; m < 4; ++m) {
        #pragma unroll
        for (int n = 0; n < 4; ++n) {
            int col = wn * 64 + n * 16 + (lane & 15);   // 0..127, parity == lane parity
            int k = col >> 1;
            #pragma unroll
            for (int r = 0; r < 4; ++r) {
                float v = acc[m][n][r];
                float pp = __shfl_xor(v, 1);
                int row = rowb + m * 16 + (lane >> 4) * 4 + r;
                float2 c = cmix[(row & 15) * 64 + k];
                float val = v * c.x + (((lane & 1) == 0) ? -pp * c.y : pp * c.y);
                ((bf16*)Cout)[(size_t)row * ldc + col] = (bf16)val;
            }
        }
    }
}

// ---------------- fused fc1 + swish + fc2 (bf16) ----------------
__global__ __launch_bounds__(256) void fc_fused(const bf16* __restrict__ H,
                                                const float* __restrict__ w1,
                                                const float* __restrict__ b1,
                                                const float* __restrict__ w2,
                                                const float* __restrict__ b2,
                                                float* __restrict__ out) {
    __shared__ bf16 sw2[8][2048];
    __shared__ bf16 ss[2048];
    int tid = threadIdx.x;
    for (int i = tid * 4; i < 8 * 2048; i += 1024) {
        float4 v = *(const float4*)(w2 + i);
        bf16x4 b = {(bf16)v.x, (bf16)v.y, (bf16)v.z, (bf16)v.w};
        *(bf16x4*)&sw2[0][i] = b;
    }

    float wv[16];
    const float4* w1p = (const float4*)(w1 + tid * 16);
    *(float4*)&wv[0]  = w1p[0];
    *(float4*)&wv[4]  = w1p[1];
    *(float4*)&wv[8]  = w1p[2];
    *(float4*)&wv[12] = w1p[3];
    float bb[8];
    const float4* b1p = (const float4*)(b1 + tid * 8);
    *(float4*)&bb[0] = b1p[0];
    *(float4*)&bb[4] = b1p[1];
    __syncthreads();

    for (int r = 0; r < 16; ++r) {
        int n = blockIdx.x * 16 + r;
        bf16x4 hv = *(const bf16x4*)(H + (size_t)n * 1024 + tid * 4);
        float hh[4] = {(float)hv[0], (float)hv[1], (float)hv[2], (float)hv[3]};
        bf16x8 sb;
        #pragma unroll
        for (int jj = 0; jj < 8; ++jj) {
            float h0 = hh[(jj >> 2) * 2];
            float h1 = hh[(jj >> 2) * 2 + 1];
            float t = h0 * wv[2 * jj] + h1 * wv[2 * jj + 1] + bb[jj];
            sb[jj] = (bf16)swishf(t);
        }
        *(bf16x8*)&ss[tid * 8] = sb;
        __syncthreads();
        int o8 = tid >> 5, l5 = tid & 31;
        float p = 0.f;
        #pragma unroll
        for (int i = 0; i < 16; ++i) {
            bf16x4 a = *(const bf16x4*)&ss[4 * l5 + 128 * i];
            bf16x4 b = *(const bf16x4*)&sw2[o8][4 * l5 + 128 * i];
            p += (float)a[0] * (float)b[0] + (float)a[1] * (float)b[1]
               + (float)a[2] * (float)b[2] + (float)a[3] * (float)b[3];
        }
        #pragma unroll
        for (int msk = 1; msk < 32; msk <<= 1) p += __shfl_xor(p, msk);
        if (l5 == 0) out[(size_t)n * 8 + o8] = p + b2[o8];
        __syncthreads();
    }
}

// ---------------- launch ----------------

extern "C" void kernel_launch(void* const* d_in, const int* in_sizes, int n_in,
                              void* d_out, int out_size, void* d_ws, size_t ws_size,
                              hipStream_t stream) {
    const float* x     = (const float*)d_in[0];
    const float* codes = (const float*)d_in[1];
    const float* p_w   = (const float*)d_in[2];
    const float* p_b   = (const float*)d_in[3];
    const float* com0  = (const float*)d_in[4];
    const float* code0 = (const float*)d_in[5];
    const float* filt0 = (const float*)d_in[6];
    const float* com1  = (const float*)d_in[7];
    const float* code1 = (const float*)d_in[8];
    const float* filt1 = (const float*)d_in[9];
    const float* w0_w  = (const float*)d_in[10];
    const float* w0_b  = (const float*)d_in[11];
    const float* w1_w  = (const float*)d_in[12];
    const float* w1_b  = (const float*)d_in[13];
    const float* fc1w  = (const float*)d_in[14];
    const float* fc1b  = (const float*)d_in[15];
    const float* fc2w  = (const float*)d_in[16];
    const float* fc2b  = (const float*)d_in[17];
    float* out = (float*)d_out;

    // fixed weight region (~7.1 MB)
    char* ws = (char*)d_ws;
    bf16*  WP   = (bf16*)(ws + 0);               // 1280x512 bf16 = 1,310,720
    bf16*  B0   = (bf16*)(ws + 1310720);         // 2,359,296
    bf16*  B1   = (bf16*)(ws + 3670016);         // 2,359,296
    bf16*  Fbb  = (bf16*)(ws + 6029312);         // 262,144
    float* Fb32 = (float*)(ws + 6291456);        // 524,288
    float* G32  = (float*)(ws + 6815744);        // 262,144
    float* bias1= (float*)(ws + 7077888);        // 5,120 (1280 f32)
    float2* cm0 = (float2*)(ws + 7083008);       // 8,192
    float2* cm1 = (float2*)(ws + 7091200);       // 8,192
    const size_t CB = 7099392;

    // row-chunk size R (multiple of 256)
    // per-row: AH region max(A0 512-col bf16 = 1024B, H3 bf16 2048B) + A1cat + A2cat
    const size_t PER_ROW = 2048 + 2304 + 2304;   // 6656
    long rmax = 0;
    if (ws_size > CB) rmax = (long)((ws_size - CB) / PER_ROW) / 256 * 256;
    if (rmax > N_ROWS) rmax = N_ROWS;            // single chunk needs ~225MB
    if (rmax < 256) {
        hipMemsetAsync(d_out, 0, (size_t)out_size * sizeof(float), stream);
        return;
    }
    const int R = (int)rmax;

    // weights (once)
    build_cmix<<<4, 256, 0, stream>>>(codes, com0, code0, filt0, cm0);
    build_cmix<<<4, 256, 0, stream>>>(codes, com1, code1, filt1, cm1);
    build_fb2<<<512, 256, 0, stream>>>(Fb32, Fbb);
    build_bcat<<<4608, 256, 0, stream>>>(w0_w, B0);
    build_bcat<<<4608, 256, 0, stream>>>(w1_w, B1);
    build_g<<<dim3(2, 32), 256, 0, stream>>>(Fb32, p_w, G32);
    build_bias1a<<<4, 256, 0, stream>>>(p_w, p_b, bias1);
    build_bias1b<<<1, 128, 0, stream>>>(Fb32, bias1);
    build_wp<<<2560, 256, 0, stream>>>(p_w, G32, WP);

    char* cb = ws + CB;
    for (int row0 = 0; row0 < N_ROWS; row0 += R) {
        const int r = (N_ROWS - row0 < R) ? (N_ROWS - row0) : R;   // multiple of 256
        bf16*  A0  = (bf16*)cb;                                    // r x 512 bf16
        bf16*  H3b = (bf16*)cb;                                    // r x 1024 bf16 (A0 dead)
        bf16*  A1  = (bf16*)(cb + (size_t)R * 2048);
        bf16*  A2  = (bf16*)(cb + (size_t)R * 2048 + (size_t)R * 2304);

        convert_x<<<r / 4, 256, 0, stream>>>(x + (size_t)row0 * 512, A0);

        // A1cat[:,0:1024] = A0@p_w[:, :512]^T + bias1; [:,1024:1152] = mix(A0@G^T + bias1B)
        gemm256<0, 1><<<dim3(r / 256, 5), 512, 0, stream>>>(
            A0, 512, WP, 512, bias1, A1, 1152, cm0, 1152, 512);
        // A2cat[:,0:1024] = swish(A1cat @ Bcat0^T + w0_b)
        gemm256<1, 0><<<dim3(r / 256, 4), 512, 0, stream>>>(
            A1, 1152, B0, 1152, w0_b, A2, 1152, nullptr, 1024, 1152);
        // A2cat[:,1024:1152] = mix(A2[:,0:1024] @ Fb^T)
        gemm_mix<<<dim3(r / 128, 1), 256, 0, stream>>>(
            A2, 1152, Fbb, 1024, (void*)(A2 + 1024), 1152, cm1, 1024);
        // H3 = A2cat @ Bcat1^T + w1_b (bf16)
        gemm256<0, 0><<<dim3(r / 256, 4), 512, 0, stream>>>(
            A2, 1152, B1, 1152, w1_b, H3b, 1024, nullptr, 1024, 1152);
        // out = fc2(swish(fc1(H3)))
        fc_fused<<<r / 16, 256, 0, stream>>>(H3b, fc1w, fc1b, fc2w, fc2b, out + (size_t)row0 * 8);
    }
}

// Round 6
// 521.938 us; speedup vs baseline: 1.1666x; 1.1666x over previous
//
#include <hip/hip_runtime.h>
#include <hip/hip_bf16.h>
#include <cstdint>

// GroupFNO1d on MI355X. Rows = B*E = 32768.
// Algebra: spectral (64 kept rFFT modes) == analysis GEMM (128 cos/-sin rows) +
// per-(e,k) complex mix + synthesis folded into next weight (K 1024->1152).
// Spectral-1 folded INTO GEMM-1 (no activation in between): GEMM-1 B-panel =
// [p_w | G=Fb@p_w], grid half of A0 folded into bias (K=512), mix in epilogue.
// Round 6: the three weight-prep kernels re-parallelized (round-5 regression:
// build_g 122us at 64 blocks / bias1a 4 blocks / bias1b 1 block, all
// latency-serialized). GEMM/mix/fc kernels byte-identical to round 4/5.

typedef __bf16 bf16;
typedef __attribute__((ext_vector_type(8))) __bf16 bf16x8;
typedef __attribute__((ext_vector_type(4))) __bf16 bf16x4;
typedef __attribute__((ext_vector_type(4))) float f32x4;

#define N_ROWS 32768

__device__ __forceinline__ void gl_lds16(const void* g, void* l) {
    __builtin_amdgcn_global_load_lds(
        (const __attribute__((address_space(1))) void*)g,
        (__attribute__((address_space(3))) void*)l,
        16, 0, 0);
}

__device__ __forceinline__ float swishf(float v) {
    return v / (1.f + __expf(-v));
}

// ---------------- setup kernels ----------------

// cmix[e*64+k] = g_k*(lam_k*com_c[k] + (1-lam_k)*(codes@code)[e,k]), g_0=1/1024 else 2/1024
__global__ __launch_bounds__(256) void build_cmix(const float* __restrict__ codes,
                                                  const float* __restrict__ com,
                                                  const float* __restrict__ code,
                                                  const float* __restrict__ filt,
                                                  float2* __restrict__ cmix) {
    int t = blockIdx.x * 256 + threadIdx.x;
    if (t >= 16 * 64) return;
    int e = t >> 6, m = t & 63;
    float er = 0.f, ei = 0.f;
    for (int c = 0; c < 64; ++c) {
        float cd = codes[e * 64 + c];
        er += cd * code[(c * 64 + m) * 2 + 0];
        ei += cd * code[(c * 64 + m) * 2 + 1];
    }
    float f = filt[m];
    float lam = fminf(fmaxf((f + 3.f) * (1.f / 6.f), 0.f), 1.f);
    float cr = lam * com[m * 2 + 0] + (1.f - lam) * er;
    float ci = lam * com[m * 2 + 1] + (1.f - lam) * ei;
    float g = (m == 0) ? (1.f / 1024.f) : (2.f / 1024.f);
    cmix[t] = make_float2(g * cr, g * ci);
}

// Fb (128 x 1024): row 2k = cos(2*pi*k*w/1024), row 2k+1 = -sin. f32 + bf16 copies.
__global__ __launch_bounds__(256) void build_fb2(float* __restrict__ Fb32,
                                                 bf16* __restrict__ Fbb) {
    int t = blockIdx.x * 256 + threadIdx.x;   // 131072
    int rr = t >> 10, s = t & 1023;
    int k = rr >> 1;
    int ph = (k * s) & 1023;
    float ang = (float)ph * 6.1359231515425649e-3f;  // 2*pi/1024
    float v = (rr & 1) ? -sinf(ang) : cosf(ang);
    Fb32[t] = v;
    Fbb[t] = (bf16)v;
}

// Bcat (1024 x 1152): cols<1024 = w[j][c]; col 1024+2k = cos(2*pi*k*j/1024), +2k+1 = -sin
__global__ __launch_bounds__(256) void build_bcat(const float* __restrict__ w,
                                                  bf16* __restrict__ out) {
    int t = blockIdx.x * 256 + threadIdx.x;
    if (t >= 1024 * 1152) return;
    int j = t / 1152, c = t % 1152;
    float v;
    if (c < 1024) {
        v = w[j * 1024 + c];
    } else {
        int cc = c - 1024, k = cc >> 1;
        int ph = (k * j) & 1023;
        float ang = (float)ph * 6.1359231515425649e-3f;
        v = (cc & 1) ? -sinf(ang) : cosf(ang);
    }
    out[t] = (bf16)v;
}

// G32[k2][c] = sum_w Fb32[k2][w] * p_w[w][c], c<512.
// grid (2, 128) = 256 blocks x 256 thr: c = bx*256+tid (coalesced), k2 = by.
// unroll 8 -> 8 outstanding loads; fb[w] is wave-uniform (scalar path).
__global__ __launch_bounds__(256) void build_g(const float* __restrict__ Fb32,
                                               const float* __restrict__ p_w,
                                               float* __restrict__ G32) {
    int c = blockIdx.x * 256 + threadIdx.x;
    int k2 = blockIdx.y;
    const float* fb = Fb32 + k2 * 1024;
    float a = 0.f;
    #pragma unroll 8
    for (int w = 0; w < 1024; ++w)
        a += fb[w] * p_w[(size_t)w * 1024 + c];
    G32[k2 * 512 + c] = a;
}

// bias1[w] = p_b[w] + sum_s (s/511)*p_w[w][512+s]. One WAVE per w (1024 waves).
__global__ __launch_bounds__(256) void build_bias1a(const float* __restrict__ p_w,
                                                    const float* __restrict__ p_b,
                                                    float* __restrict__ bias1) {
    int w = (blockIdx.x * 256 + threadIdx.x) >> 6;   // 0..1023
    int lane = threadIdx.x & 63;
    const float* src = p_w + (size_t)w * 1024 + 512 + lane * 8;
    float4 v0 = *(const float4*)(src);
    float4 v1 = *(const float4*)(src + 4);
    float s0 = (float)(lane * 8) * (1.f / 511.f);
    const float st = 1.f / 511.f;
    float a = v0.x * s0 + v0.y * (s0 + st) + v0.z * (s0 + 2 * st) + v0.w * (s0 + 3 * st)
            + v1.x * (s0 + 4 * st) + v1.y * (s0 + 5 * st) + v1.z * (s0 + 6 * st) + v1.w * (s0 + 7 * st);
    #pragma unroll
    for (int msk = 1; msk < 64; msk <<= 1) a += __shfl_xor(a, msk);
    if (lane == 0) bias1[w] = p_b[w] + a;
}

// bias1[1024+k2] = sum_w Fb32[k2][w]*bias1[w]; zero 1152..1279. One WAVE per k2.
__global__ __launch_bounds__(256) void build_bias1b(const float* __restrict__ Fb32,
                                                    float* __restrict__ bias1) {
    int k2 = blockIdx.x * 4 + (threadIdx.x >> 6);    // 32 blocks -> 0..127
    int lane = threadIdx.x & 63;
    const float* fb = Fb32 + (size_t)k2 * 1024 + lane * 16;
    const float* bb = bias1 + lane * 16;
    float a = 0.f;
    #pragma unroll
    for (int j = 0; j < 4; ++j) {
        float4 f = *(const float4*)(fb + 4 * j);
        float4 b = *(const float4*)(bb + 4 * j);
        a += f.x * b.x + f.y * b.y + f.z * b.z + f.w * b.w;
    }
    #pragma unroll
    for (int msk = 1; msk < 64; msk <<= 1) a += __shfl_xor(a, msk);
    if (lane == 0) {
        bias1[1024 + k2] = a;
        bias1[1152 + k2] = 0.f;
    }
}

// WP (1280 x 512 bf16): rows<1024 = p_w[r][c]; 1024..1151 = G32; >=1152 = 0
__global__ __launch_bounds__(256) void build_wp(const float* __restrict__ p_w,
                                                const float* __restrict__ G32,
                                                bf16* __restrict__ WP) {
    int t = blockIdx.x * 256 + threadIdx.x;   // 655360
    if (t >= 1280 * 512) return;
    int r = t >> 9, c = t & 511;
    float v = (r < 1024) ? p_w[(size_t)r * 1024 + c]
            : (r < 1152) ? G32[(r - 1024) * 512 + c] : 0.f;
    WP[t] = (bf16)v;
}

// A0[n][c] = bf16(x[n*512+c])
__global__ __launch_bounds__(256) void convert_x(const float* __restrict__ x,
                                                 bf16* __restrict__ A0) {
    int t = blockIdx.x * 256 + threadIdx.x;
    const float4* xp = (const float4*)(x + (size_t)t * 8);
    float4 a = xp[0], b = xp[1];
    bf16x8 o;
    o[0] = (bf16)a.x; o[1] = (bf16)a.y; o[2] = (bf16)a.z; o[3] = (bf16)a.w;
    o[4] = (bf16)b.x; o[5] = (bf16)b.y; o[6] = (bf16)b.z; o[7] = (bf16)b.w;
    *(bf16x8*)(A0 + (size_t)t * 8) = o;
}

// ---------------- big GEMM: 256x256 tile, BK=64, T2 swizzle (round-4 proven) -------
template<int ACT, int HASMIX>
__global__ __launch_bounds__(512, 2)
void gemm256(const bf16* __restrict__ A, int lda,
             const bf16* __restrict__ Bt, int ldb,
             const float* __restrict__ bias,
             bf16* __restrict__ Cout, int ldc,
             const float2* __restrict__ cmix, int ncols,
             int K) {
    __shared__ bf16 sA[2][256 * 64];
    __shared__ bf16 sB[2][256 * 64];
    const int tid = threadIdx.x;
    const int wave = tid >> 6, lane = tid & 63;
    const int wm = wave >> 2, wn = wave & 3;
    const int rowA0 = blockIdx.x * 256;
    const int rowB0 = blockIdx.y * 256;

    f32x4 acc[8][4];
    #pragma unroll
    for (int m = 0; m < 8; ++m)
        #pragma unroll
        for (int n = 0; n < 4; ++n)
            acc[m][n] = f32x4{0.f, 0.f, 0.f, 0.f};

    const int srq = lane >> 3;                 // row within 8-row group
    const int ssl = (lane & 7) ^ srq;          // inverse-swizzled 16B col slot
    const bf16* gA = A + (size_t)(rowA0 + wave * 8 + srq) * lda + ssl * 8;
    const bf16* gB = Bt + (size_t)(rowB0 + wave * 8 + srq) * ldb + ssl * 8;

    const int NT = K / 64;
    auto STAGE = [&](int t) {
        const int slot = t & 1;
        const size_t ko = (size_t)t * 64;
        #pragma unroll
        for (int j = 0; j < 4; ++j) {
            gl_lds16(gA + (size_t)j * 64 * lda + ko, &sA[slot][(j * 64 + wave * 8) * 64]);
            gl_lds16(gB + (size_t)j * 64 * ldb + ko, &sB[slot][(j * 64 + wave * 8) * 64]);
        }
    };

    STAGE(0);

    const int p = lane & 15, q = lane >> 4;
    const int axr = (p & 7) << 4;              // read-side byte XOR

    for (int t = 0; t < NT; ++t) {
        asm volatile("s_waitcnt vmcnt(0)" ::: "memory");
        __builtin_amdgcn_s_barrier();
        __builtin_amdgcn_sched_barrier(0);
        if (t + 1 < NT) STAGE(t + 1);
        const char* sa = (const char*)sA[t & 1];
        const char* sb = (const char*)sB[t & 1];
        #pragma unroll
        for (int kk = 0; kk < 64; kk += 32) {
            bf16x8 af[8], bfr[4];
            #pragma unroll
            for (int m = 0; m < 8; ++m) {
                int off = (((wm * 128 + m * 16 + p) * 64 + kk + q * 8) * 2) ^ axr;
                af[m] = *(const bf16x8*)(sa + off);
            }
            #pragma unroll
            for (int n = 0; n < 4; ++n) {
                int off = (((wn * 64 + n * 16 + p) * 64 + kk + q * 8) * 2) ^ axr;
                bfr[n] = *(const bf16x8*)(sb + off);
            }
            asm volatile("s_waitcnt lgkmcnt(0)" ::: "memory");
            __builtin_amdgcn_sched_barrier(0);
            __builtin_amdgcn_s_setprio(1);
            #pragma unroll
            for (int m = 0; m < 8; ++m)
                #pragma unroll
                for (int n = 0; n < 4; ++n)
                    acc[m][n] = __builtin_amdgcn_mfma_f32_16x16x32_bf16(af[m], bfr[n], acc[m][n], 0, 0, 0);
            __builtin_amdgcn_s_setprio(0);
            __builtin_amdgcn_sched_barrier(0);
        }
    }

    const int rowb = rowA0 + wm * 128;
    const int colb = rowB0 + wn * 64;
    #pragma unroll
    for (int m = 0; m < 8; ++m) {
        #pragma unroll
        for (int n = 0; n < 4; ++n) {
            int col = colb + n * 16 + p;
            float bv = bias ? bias[col] : 0.f;
            #pragma unroll
            for (int r = 0; r < 4; ++r) {
                int row = rowb + m * 16 + q * 4 + r;
                float v = acc[m][n][r] + bv;
                if (HASMIX) {
                    float pp = __shfl_xor(v, 1);       // partner col (uniform exec)
                    if (col >= 1024) {
                        int k = (col - 1024) >> 1;
                        float2 c = cmix[(row & 15) * 64 + k];
                        v = v * c.x + (((p & 1) == 0) ? -pp * c.y : pp * c.y);
                    }
                    if (col < ncols) Cout[(size_t)row * ldc + col] = (bf16)v;
                } else {
                    if (ACT) v = swishf(v);
                    Cout[(size_t)row * ldc + col] = (bf16)v;
                }
            }
        }
    }
}

// ---------------- 128^2 GEMM for the layer-2 analysis+mix step ----------------
__global__ __launch_bounds__(256)
void gemm_mix(const bf16* __restrict__ A, int lda,
              const bf16* __restrict__ Bt, int ldb,
              void* __restrict__ Cout, int ldc,
              const float2* __restrict__ cmix,
              int K) {
    __shared__ bf16 sA[128 * 64];
    __shared__ bf16 sB[128 * 64];
    const int tid = threadIdx.x;
    const int wave = tid >> 6;
    const int lane = tid & 63;
    const int wm = wave >> 1, wn = wave & 1;
    const int rowA0 = blockIdx.x * 128;

    f32x4 acc[4][4];
    #pragma unroll
    for (int m = 0; m < 4; ++m)
        #pragma unroll
        for (int n = 0; n < 4; ++n)
            acc[m][n] = f32x4{0.f, 0.f, 0.f, 0.f};

    const int srow = wave * 32 + (lane >> 3);
    const int scol = (lane & 7) * 8;
    const bf16* gA = A + (size_t)(rowA0 + srow) * lda + scol;
    const bf16* gB = Bt + (size_t)srow * ldb + scol;
    bf16* lA = &sA[(wave * 32) * 64];
    bf16* lB = &sB[(wave * 32) * 64];

    for (int k0 = 0; k0 < K; k0 += 64) {
        __syncthreads();
        #pragma unroll
        for (int i = 0; i < 4; ++i) {
            gl_lds16(gA + (size_t)i * 8 * lda + k0, lA + i * 8 * 64);
            gl_lds16(gB + (size_t)i * 8 * ldb + k0, lB + i * 8 * 64);
        }
        __syncthreads();
        #pragma unroll
        for (int kk = 0; kk < 64; kk += 32) {
            bf16x8 af[4], bfr[4];
            #pragma unroll
            for (int m = 0; m < 4; ++m)
                af[m] = *(const bf16x8*)&sA[(wm * 64 + m * 16 + (lane & 15)) * 64 + kk + ((lane >> 4) * 8)];
            #pragma unroll
            for (int n = 0; n < 4; ++n)
                bfr[n] = *(const bf16x8*)&sB[(wn * 64 + n * 16 + (lane & 15)) * 64 + kk + ((lane >> 4) * 8)];
            #pragma unroll
            for (int m = 0; m < 4; ++m)
                #pragma unroll
                for (int n = 0; n < 4; ++n)
                    acc[m][n] = __builtin_amdgcn_mfma_f32_16x16x32_bf16(af[m], bfr[n], acc[m][n], 0, 0, 0);
        }
    }

    const int rowb = rowA0 + wm * 64;
    #pragma unroll
    for (int m = 0; m < 4; ++m) {
        #pragma unroll
        for (int n = 0; n < 4; ++n) {
            int col = wn * 64 + n * 16 + (lane & 15);
            int k = col >> 1;
            #pragma unroll
            for (int r = 0; r < 4; ++r) {
                float v = acc[m][n][r];
                float pp = __shfl_xor(v, 1);
                int row = rowb + m * 16 + (lane >> 4) * 4 + r;
                float2 c = cmix[(row & 15) * 64 + k];
                float val = v * c.x + (((lane & 1) == 0) ? -pp * c.y : pp * c.y);
                ((bf16*)Cout)[(size_t)row * ldc + col] = (bf16)val;
            }
        }
    }
}

// ---------------- fused fc1 + swish + fc2 (bf16) ----------------
__global__ __launch_bounds__(256) void fc_fused(const bf16* __restrict__ H,
                                                const float* __restrict__ w1,
                                                const float* __restrict__ b1,
                                                const float* __restrict__ w2,
                                                const float* __restrict__ b2,
                                                float* __restrict__ out) {
    __shared__ bf16 sw2[8][2048];
    __shared__ bf16 ss[2048];
    int tid = threadIdx.x;
    for (int i = tid * 4; i < 8 * 2048; i += 1024) {
        float4 v = *(const float4*)(w2 + i);
        bf16x4 b = {(bf16)v.x, (bf16)v.y, (bf16)v.z, (bf16)v.w};
        *(bf16x4*)&sw2[0][i] = b;
    }

    float wv[16];
    const float4* w1p = (const float4*)(w1 + tid * 16);
    *(float4*)&wv[0]  = w1p[0];
    *(float4*)&wv[4]  = w1p[1];
    *(float4*)&wv[8]  = w1p[2];
    *(float4*)&wv[12] = w1p[3];
    float bb[8];
    const float4* b1p = (const float4*)(b1 + tid * 8);
    *(float4*)&bb[0] = b1p[0];
    *(float4*)&bb[4] = b1p[1];
    __syncthreads();

    for (int r = 0; r < 16; ++r) {
        int n = blockIdx.x * 16 + r;
        bf16x4 hv = *(const bf16x4*)(H + (size_t)n * 1024 + tid * 4);
        float hh[4] = {(float)hv[0], (float)hv[1], (float)hv[2], (float)hv[3]};
        bf16x8 sb;
        #pragma unroll
        for (int jj = 0; jj < 8; ++jj) {
            float h0 = hh[(jj >> 2) * 2];
            float h1 = hh[(jj >> 2) * 2 + 1];
            float t = h0 * wv[2 * jj] + h1 * wv[2 * jj + 1] + bb[jj];
            sb[jj] = (bf16)swishf(t);
        }
        *(bf16x8*)&ss[tid * 8] = sb;
        __syncthreads();
        int o8 = tid >> 5, l5 = tid & 31;
        float p = 0.f;
        #pragma unroll
        for (int i = 0; i < 16; ++i) {
            bf16x4 a = *(const bf16x4*)&ss[4 * l5 + 128 * i];
            bf16x4 b = *(const bf16x4*)&sw2[o8][4 * l5 + 128 * i];
            p += (float)a[0] * (float)b[0] + (float)a[1] * (float)b[1]
               + (float)a[2] * (float)b[2] + (float)a[3] * (float)b[3];
        }
        #pragma unroll
        for (int msk = 1; msk < 32; msk <<= 1) p += __shfl_xor(p, msk);
        if (l5 == 0) out[(size_t)n * 8 + o8] = p + b2[o8];
        __syncthreads();
    }
}

// ---------------- launch ----------------

extern "C" void kernel_launch(void* const* d_in, const int* in_sizes, int n_in,
                              void* d_out, int out_size, void* d_ws, size_t ws_size,
                              hipStream_t stream) {
    const float* x     = (const float*)d_in[0];
    const float* codes = (const float*)d_in[1];
    const float* p_w   = (const float*)d_in[2];
    const float* p_b   = (const float*)d_in[3];
    const float* com0  = (const float*)d_in[4];
    const float* code0 = (const float*)d_in[5];
    const float* filt0 = (const float*)d_in[6];
    const float* com1  = (const float*)d_in[7];
    const float* code1 = (const float*)d_in[8];
    const float* filt1 = (const float*)d_in[9];
    const float* w0_w  = (const float*)d_in[10];
    const float* w0_b  = (const float*)d_in[11];
    const float* w1_w  = (const float*)d_in[12];
    const float* w1_b  = (const float*)d_in[13];
    const float* fc1w  = (const float*)d_in[14];
    const float* fc1b  = (const float*)d_in[15];
    const float* fc2w  = (const float*)d_in[16];
    const float* fc2b  = (const float*)d_in[17];
    float* out = (float*)d_out;

    // fixed weight region (~7.1 MB)
    char* ws = (char*)d_ws;
    bf16*  WP   = (bf16*)(ws + 0);               // 1280x512 bf16 = 1,310,720
    bf16*  B0   = (bf16*)(ws + 1310720);         // 2,359,296
    bf16*  B1   = (bf16*)(ws + 3670016);         // 2,359,296
    bf16*  Fbb  = (bf16*)(ws + 6029312);         // 262,144
    float* Fb32 = (float*)(ws + 6291456);        // 524,288
    float* G32  = (float*)(ws + 6815744);        // 262,144
    float* bias1= (float*)(ws + 7077888);        // 5,120 (1280 f32)
    float2* cm0 = (float2*)(ws + 7083008);       // 8,192
    float2* cm1 = (float2*)(ws + 7091200);       // 8,192
    const size_t CB = 7099392;

    // row-chunk size R (multiple of 256)
    const size_t PER_ROW = 2048 + 2304 + 2304;   // 6656
    long rmax = 0;
    if (ws_size > CB) rmax = (long)((ws_size - CB) / PER_ROW) / 256 * 256;
    if (rmax > N_ROWS) rmax = N_ROWS;            // single chunk needs ~225MB
    if (rmax < 256) {
        hipMemsetAsync(d_out, 0, (size_t)out_size * sizeof(float), stream);
        return;
    }
    const int R = (int)rmax;

    // weights (once)
    build_cmix<<<4, 256, 0, stream>>>(codes, com0, code0, filt0, cm0);
    build_cmix<<<4, 256, 0, stream>>>(codes, com1, code1, filt1, cm1);
    build_fb2<<<512, 256, 0, stream>>>(Fb32, Fbb);
    build_bcat<<<4608, 256, 0, stream>>>(w0_w, B0);
    build_bcat<<<4608, 256, 0, stream>>>(w1_w, B1);
    build_g<<<dim3(2, 128), 256, 0, stream>>>(Fb32, p_w, G32);
    build_bias1a<<<256, 256, 0, stream>>>(p_w, p_b, bias1);
    build_bias1b<<<32, 256, 0, stream>>>(Fb32, bias1);
    build_wp<<<2560, 256, 0, stream>>>(p_w, G32, WP);

    char* cb = ws + CB;
    for (int row0 = 0; row0 < N_ROWS; row0 += R) {
        const int r = (N_ROWS - row0 < R) ? (N_ROWS - row0) : R;   // multiple of 256
        bf16*  A0  = (bf16*)cb;                                    // r x 512 bf16
        bf16*  H3b = (bf16*)cb;                                    // r x 1024 bf16 (A0 dead)
        bf16*  A1  = (bf16*)(cb + (size_t)R * 2048);
        bf16*  A2  = (bf16*)(cb + (size_t)R * 2048 + (size_t)R * 2304);

        convert_x<<<r / 4, 256, 0, stream>>>(x + (size_t)row0 * 512, A0);

        // A1cat[:,0:1024] = A0@p_w[:, :512]^T + bias1; [:,1024:1152] = mix(A0@G^T + bias1B)
        gemm256<0, 1><<<dim3(r / 256, 5), 512, 0, stream>>>(
            A0, 512, WP, 512, bias1, A1, 1152, cm0, 1152, 512);
        // A2cat[:,0:1024] = swish(A1cat @ Bcat0^T + w0_b)
        gemm256<1, 0><<<dim3(r / 256, 4), 512, 0, stream>>>(
            A1, 1152, B0, 1152, w0_b, A2, 1152, nullptr, 1024, 1152);
        // A2cat[:,1024:1152] = mix(A2[:,0:1024] @ Fb^T)
        gemm_mix<<<dim3(r / 128, 1), 256, 0, stream>>>(
            A2, 1152, Fbb, 1024, (void*)(A2 + 1024), 1152, cm1, 1024);
        // H3 = A2cat @ Bcat1^T + w1_b (bf16)
        gemm256<0, 0><<<dim3(r / 256, 4), 512, 0, stream>>>(
            A2, 1152, B1, 1152, w1_b, H3b, 1024, nullptr, 1024, 1152);
        // out = fc2(swish(fc1(H3)))
        fc_fused<<<r / 16, 256, 0, stream>>>(H3b, fc1w, fc1b, fc2w, fc2b, out + (size_t)row0 * 8);
    }
}

// Round 7
// 512.376 us; speedup vs baseline: 1.1884x; 1.0187x over previous
//
#include <hip/hip_runtime.h>
#include <hip/hip_bf16.h>
#include <cstdint>

// GroupFNO1d on MI355X. Rows = B*E = 32768.
// Algebra: spectral (64 kept rFFT modes) == analysis GEMM (128 cos/-sin rows) +
// per-(e,k) complex mix + synthesis folded into next weight (K 1024->1152).
// Spectral-1 folded INTO GEMM-1: B-panel = [p_w | G=Fb@p_w], grid half of A0
// folded into bias (K=512), mix in epilogue.
// Round 7: XCD-aware 1D-grid decode in gemm256 (bid%8 -> xcd, y-fastest within
// XCD) so blocks sharing an A-row-tile are co-resident on one XCD -> A re-reads
// served from that XCD's L2 instead of streaming ~5.4 TB/s through L3 (the
// round-6 bottleneck: MfmaUtil 28%, HBM 17%, conflicts 0 => cache-BW bound).
// Per-block math bit-identical to round 6.

typedef __bf16 bf16;
typedef __attribute__((ext_vector_type(8))) __bf16 bf16x8;
typedef __attribute__((ext_vector_type(4))) __bf16 bf16x4;
typedef __attribute__((ext_vector_type(4))) float f32x4;

#define N_ROWS 32768

__device__ __forceinline__ void gl_lds16(const void* g, void* l) {
    __builtin_amdgcn_global_load_lds(
        (const __attribute__((address_space(1))) void*)g,
        (__attribute__((address_space(3))) void*)l,
        16, 0, 0);
}

__device__ __forceinline__ float swishf(float v) {
    return v / (1.f + __expf(-v));
}

// ---------------- setup kernels ----------------

__global__ __launch_bounds__(256) void build_cmix(const float* __restrict__ codes,
                                                  const float* __restrict__ com,
                                                  const float* __restrict__ code,
                                                  const float* __restrict__ filt,
                                                  float2* __restrict__ cmix) {
    int t = blockIdx.x * 256 + threadIdx.x;
    if (t >= 16 * 64) return;
    int e = t >> 6, m = t & 63;
    float er = 0.f, ei = 0.f;
    for (int c = 0; c < 64; ++c) {
        float cd = codes[e * 64 + c];
        er += cd * code[(c * 64 + m) * 2 + 0];
        ei += cd * code[(c * 64 + m) * 2 + 1];
    }
    float f = filt[m];
    float lam = fminf(fmaxf((f + 3.f) * (1.f / 6.f), 0.f), 1.f);
    float cr = lam * com[m * 2 + 0] + (1.f - lam) * er;
    float ci = lam * com[m * 2 + 1] + (1.f - lam) * ei;
    float g = (m == 0) ? (1.f / 1024.f) : (2.f / 1024.f);
    cmix[t] = make_float2(g * cr, g * ci);
}

__global__ __launch_bounds__(256) void build_fb2(float* __restrict__ Fb32,
                                                 bf16* __restrict__ Fbb) {
    int t = blockIdx.x * 256 + threadIdx.x;   // 131072
    int rr = t >> 10, s = t & 1023;
    int k = rr >> 1;
    int ph = (k * s) & 1023;
    float ang = (float)ph * 6.1359231515425649e-3f;  // 2*pi/1024
    float v = (rr & 1) ? -sinf(ang) : cosf(ang);
    Fb32[t] = v;
    Fbb[t] = (bf16)v;
}

__global__ __launch_bounds__(256) void build_bcat(const float* __restrict__ w,
                                                  bf16* __restrict__ out) {
    int t = blockIdx.x * 256 + threadIdx.x;
    if (t >= 1024 * 1152) return;
    int j = t / 1152, c = t % 1152;
    float v;
    if (c < 1024) {
        v = w[j * 1024 + c];
    } else {
        int cc = c - 1024, k = cc >> 1;
        int ph = (k * j) & 1023;
        float ang = (float)ph * 6.1359231515425649e-3f;
        v = (cc & 1) ? -sinf(ang) : cosf(ang);
    }
    out[t] = (bf16)v;
}

// G32[k2][c] = sum_w Fb32[k2][w] * p_w[w][c], c<512. grid (2,128), coalesced.
__global__ __launch_bounds__(256) void build_g(const float* __restrict__ Fb32,
                                               const float* __restrict__ p_w,
                                               float* __restrict__ G32) {
    int c = blockIdx.x * 256 + threadIdx.x;
    int k2 = blockIdx.y;
    const float* fb = Fb32 + k2 * 1024;
    float a = 0.f;
    #pragma unroll 8
    for (int w = 0; w < 1024; ++w)
        a += fb[w] * p_w[(size_t)w * 1024 + c];
    G32[k2 * 512 + c] = a;
}

// bias1[w] = p_b[w] + sum_s (s/511)*p_w[w][512+s]. One WAVE per w.
__global__ __launch_bounds__(256) void build_bias1a(const float* __restrict__ p_w,
                                                    const float* __restrict__ p_b,
                                                    float* __restrict__ bias1) {
    int w = (blockIdx.x * 256 + threadIdx.x) >> 6;
    int lane = threadIdx.x & 63;
    const float* src = p_w + (size_t)w * 1024 + 512 + lane * 8;
    float4 v0 = *(const float4*)(src);
    float4 v1 = *(const float4*)(src + 4);
    float s0 = (float)(lane * 8) * (1.f / 511.f);
    const float st = 1.f / 511.f;
    float a = v0.x * s0 + v0.y * (s0 + st) + v0.z * (s0 + 2 * st) + v0.w * (s0 + 3 * st)
            + v1.x * (s0 + 4 * st) + v1.y * (s0 + 5 * st) + v1.z * (s0 + 6 * st) + v1.w * (s0 + 7 * st);
    #pragma unroll
    for (int msk = 1; msk < 64; msk <<= 1) a += __shfl_xor(a, msk);
    if (lane == 0) bias1[w] = p_b[w] + a;
}

// bias1[1024+k2] = sum_w Fb32[k2][w]*bias1[w]; zero 1152..1279. One WAVE per k2.
__global__ __launch_bounds__(256) void build_bias1b(const float* __restrict__ Fb32,
                                                    float* __restrict__ bias1) {
    int k2 = blockIdx.x * 4 + (threadIdx.x >> 6);
    int lane = threadIdx.x & 63;
    const float* fb = Fb32 + (size_t)k2 * 1024 + lane * 16;
    const float* bb = bias1 + lane * 16;
    float a = 0.f;
    #pragma unroll
    for (int j = 0; j < 4; ++j) {
        float4 f = *(const float4*)(fb + 4 * j);
        float4 b = *(const float4*)(bb + 4 * j);
        a += f.x * b.x + f.y * b.y + f.z * b.z + f.w * b.w;
    }
    #pragma unroll
    for (int msk = 1; msk < 64; msk <<= 1) a += __shfl_xor(a, msk);
    if (lane == 0) {
        bias1[1024 + k2] = a;
        bias1[1152 + k2] = 0.f;
    }
}

// WP (1280 x 512 bf16): rows<1024 = p_w[r][c]; 1024..1151 = G32; >=1152 = 0
__global__ __launch_bounds__(256) void build_wp(const float* __restrict__ p_w,
                                                const float* __restrict__ G32,
                                                bf16* __restrict__ WP) {
    int t = blockIdx.x * 256 + threadIdx.x;
    if (t >= 1280 * 512) return;
    int r = t >> 9, c = t & 511;
    float v = (r < 1024) ? p_w[(size_t)r * 1024 + c]
            : (r < 1152) ? G32[(r - 1024) * 512 + c] : 0.f;
    WP[t] = (bf16)v;
}

__global__ __launch_bounds__(256) void convert_x(const float* __restrict__ x,
                                                 bf16* __restrict__ A0) {
    int t = blockIdx.x * 256 + threadIdx.x;
    const float4* xp = (const float4*)(x + (size_t)t * 8);
    float4 a = xp[0], b = xp[1];
    bf16x8 o;
    o[0] = (bf16)a.x; o[1] = (bf16)a.y; o[2] = (bf16)a.z; o[3] = (bf16)a.w;
    o[4] = (bf16)b.x; o[5] = (bf16)b.y; o[6] = (bf16)b.z; o[7] = (bf16)b.w;
    *(bf16x8*)(A0 + (size_t)t * 8) = o;
}

// ---------------- big GEMM: 256x256 tile, BK=64, T2 swizzle, XCD-aware grid -------
// 1D grid of NX*NY blocks. Decode (NX%8==0): xcd=bid&7, pos=bid>>3, ty=pos%NY,
// tx=(pos/NY)*8+xcd  -> consecutive blocks on one XCD cover all NY col-panels of
// the same A-row-tiles => A re-reads are L2-local. Identity fallback otherwise.
template<int ACT, int HASMIX>
__global__ __launch_bounds__(512, 2)
void gemm256(const bf16* __restrict__ A, int lda,
             const bf16* __restrict__ Bt, int ldb,
             const float* __restrict__ bias,
             bf16* __restrict__ Cout, int ldc,
             const float2* __restrict__ cmix, int ncols,
             int K, int NX, int NY) {
    __shared__ bf16 sA[2][256 * 64];
    __shared__ bf16 sB[2][256 * 64];
    const int tid = threadIdx.x;
    const int wave = tid >> 6, lane = tid & 63;
    const int wm = wave >> 2, wn = wave & 3;

    int tx, ty;
    if ((NX & 7) == 0) {
        int xcd = blockIdx.x & 7;
        int pos = blockIdx.x >> 3;
        ty = pos % NY;
        tx = (pos / NY) * 8 + xcd;
    } else {
        tx = blockIdx.x % NX;
        ty = blockIdx.x / NX;
    }
    const int rowA0 = tx * 256;
    const int rowB0 = ty * 256;

    f32x4 acc[8][4];
    #pragma unroll
    for (int m = 0; m < 8; ++m)
        #pragma unroll
        for (int n = 0; n < 4; ++n)
            acc[m][n] = f32x4{0.f, 0.f, 0.f, 0.f};

    const int srq = lane >> 3;                 // row within 8-row group
    const int ssl = (lane & 7) ^ srq;          // inverse-swizzled 16B col slot
    const bf16* gA = A + (size_t)(rowA0 + wave * 8 + srq) * lda + ssl * 8;
    const bf16* gB = Bt + (size_t)(rowB0 + wave * 8 + srq) * ldb + ssl * 8;

    const int NT = K / 64;
    auto STAGE = [&](int t) {
        const int slot = t & 1;
        const size_t ko = (size_t)t * 64;
        #pragma unroll
        for (int j = 0; j < 4; ++j) {
            gl_lds16(gA + (size_t)j * 64 * lda + ko, &sA[slot][(j * 64 + wave * 8) * 64]);
            gl_lds16(gB + (size_t)j * 64 * ldb + ko, &sB[slot][(j * 64 + wave * 8) * 64]);
        }
    };

    STAGE(0);

    const int p = lane & 15, q = lane >> 4;
    const int axr = (p & 7) << 4;              // read-side byte XOR

    for (int t = 0; t < NT; ++t) {
        asm volatile("s_waitcnt vmcnt(0)" ::: "memory");
        __builtin_amdgcn_s_barrier();
        __builtin_amdgcn_sched_barrier(0);
        if (t + 1 < NT) STAGE(t + 1);
        const char* sa = (const char*)sA[t & 1];
        const char* sb = (const char*)sB[t & 1];
        #pragma unroll
        for (int kk = 0; kk < 64; kk += 32) {
            bf16x8 af[8], bfr[4];
            #pragma unroll
            for (int m = 0; m < 8; ++m) {
                int off = (((wm * 128 + m * 16 + p) * 64 + kk + q * 8) * 2) ^ axr;
                af[m] = *(const bf16x8*)(sa + off);
            }
            #pragma unroll
            for (int n = 0; n < 4; ++n) {
                int off = (((wn * 64 + n * 16 + p) * 64 + kk + q * 8) * 2) ^ axr;
                bfr[n] = *(const bf16x8*)(sb + off);
            }
            asm volatile("s_waitcnt lgkmcnt(0)" ::: "memory");
            __builtin_amdgcn_sched_barrier(0);
            __builtin_amdgcn_s_setprio(1);
            #pragma unroll
            for (int m = 0; m < 8; ++m)
                #pragma unroll
                for (int n = 0; n < 4; ++n)
                    acc[m][n] = __builtin_amdgcn_mfma_f32_16x16x32_bf16(af[m], bfr[n], acc[m][n], 0, 0, 0);
            __builtin_amdgcn_s_setprio(0);
            __builtin_amdgcn_sched_barrier(0);
        }
    }

    const int rowb = rowA0 + wm * 128;
    const int colb = rowB0 + wn * 64;
    #pragma unroll
    for (int m = 0; m < 8; ++m) {
        #pragma unroll
        for (int n = 0; n < 4; ++n) {
            int col = colb + n * 16 + p;
            float bv = bias ? bias[col] : 0.f;
            #pragma unroll
            for (int r = 0; r < 4; ++r) {
                int row = rowb + m * 16 + q * 4 + r;
                float v = acc[m][n][r] + bv;
                if (HASMIX) {
                    float pp = __shfl_xor(v, 1);       // partner col (uniform exec)
                    if (col >= 1024) {
                        int k = (col - 1024) >> 1;
                        float2 c = cmix[(row & 15) * 64 + k];
                        v = v * c.x + (((p & 1) == 0) ? -pp * c.y : pp * c.y);
                    }
                    if (col < ncols) Cout[(size_t)row * ldc + col] = (bf16)v;
                } else {
                    if (ACT) v = swishf(v);
                    Cout[(size_t)row * ldc + col] = (bf16)v;
                }
            }
        }
    }
}

// ---------------- 128^2 GEMM for the layer-2 analysis+mix step ----------------
__global__ __launch_bounds__(256)
void gemm_mix(const bf16* __restrict__ A, int lda,
              const bf16* __restrict__ Bt, int ldb,
              void* __restrict__ Cout, int ldc,
              const float2* __restrict__ cmix,
              int K) {
    __shared__ bf16 sA[128 * 64];
    __shared__ bf16 sB[128 * 64];
    const int tid = threadIdx.x;
    const int wave = tid >> 6;
    const int lane = tid & 63;
    const int wm = wave >> 1, wn = wave & 1;
    const int rowA0 = blockIdx.x * 128;

    f32x4 acc[4][4];
    #pragma unroll
    for (int m = 0; m < 4; ++m)
        #pragma unroll
        for (int n = 0; n < 4; ++n)
            acc[m][n] = f32x4{0.f, 0.f, 0.f, 0.f};

    const int srow = wave * 32 + (lane >> 3);
    const int scol = (lane & 7) * 8;
    const bf16* gA = A + (size_t)(rowA0 + srow) * lda + scol;
    const bf16* gB = Bt + (size_t)srow * ldb + scol;
    bf16* lA = &sA[(wave * 32) * 64];
    bf16* lB = &sB[(wave * 32) * 64];

    for (int k0 = 0; k0 < K; k0 += 64) {
        __syncthreads();
        #pragma unroll
        for (int i = 0; i < 4; ++i) {
            gl_lds16(gA + (size_t)i * 8 * lda + k0, lA + i * 8 * 64);
            gl_lds16(gB + (size_t)i * 8 * ldb + k0, lB + i * 8 * 64);
        }
        __syncthreads();
        #pragma unroll
        for (int kk = 0; kk < 64; kk += 32) {
            bf16x8 af[4], bfr[4];
            #pragma unroll
            for (int m = 0; m < 4; ++m)
                af[m] = *(const bf16x8*)&sA[(wm * 64 + m * 16 + (lane & 15)) * 64 + kk + ((lane >> 4) * 8)];
            #pragma unroll
            for (int n = 0; n < 4; ++n)
                bfr[n] = *(const bf16x8*)&sB[(wn * 64 + n * 16 + (lane & 15)) * 64 + kk + ((lane >> 4) * 8)];
            #pragma unroll
            for (int m = 0; m < 4; ++m)
                #pragma unroll
                for (int n = 0; n < 4; ++n)
                    acc[m][n] = __builtin_amdgcn_mfma_f32_16x16x32_bf16(af[m], bfr[n], acc[m][n], 0, 0, 0);
        }
    }

    const int rowb = rowA0 + wm * 64;
    #pragma unroll
    for (int m = 0; m < 4; ++m) {
        #pragma unroll
        for (int n = 0; n < 4; ++n) {
            int col = wn * 64 + n * 16 + (lane & 15);
            int k = col >> 1;
            #pragma unroll
            for (int r = 0; r < 4; ++r) {
                float v = acc[m][n][r];
                float pp = __shfl_xor(v, 1);
                int row = rowb + m * 16 + (lane >> 4) * 4 + r;
                float2 c = cmix[(row & 15) * 64 + k];
                float val = v * c.x + (((lane & 1) == 0) ? -pp * c.y : pp * c.y);
                ((bf16*)Cout)[(size_t)row * ldc + col] = (bf16)val;
            }
        }
    }
}

// ---------------- fused fc1 + swish + fc2 (bf16) ----------------
__global__ __launch_bounds__(256) void fc_fused(const bf16* __restrict__ H,
                                                const float* __restrict__ w1,
                                                const float* __restrict__ b1,
                                                const float* __restrict__ w2,
                                                const float* __restrict__ b2,
                                                float* __restrict__ out) {
    __shared__ bf16 sw2[8][2048];
    __shared__ bf16 ss[2048];
    int tid = threadIdx.x;
    for (int i = tid * 4; i < 8 * 2048; i += 1024) {
        float4 v = *(const float4*)(w2 + i);
        bf16x4 b = {(bf16)v.x, (bf16)v.y, (bf16)v.z, (bf16)v.w};
        *(bf16x4*)&sw2[0][i] = b;
    }

    float wv[16];
    const float4* w1p = (const float4*)(w1 + tid * 16);
    *(float4*)&wv[0]  = w1p[0];
    *(float4*)&wv[4]  = w1p[1];
    *(float4*)&wv[8]  = w1p[2];
    *(float4*)&wv[12] = w1p[3];
    float bb[8];
    const float4* b1p = (const float4*)(b1 + tid * 8);
    *(float4*)&bb[0] = b1p[0];
    *(float4*)&bb[4] = b1p[1];
    __syncthreads();

    for (int r = 0; r < 16; ++r) {
        int n = blockIdx.x * 16 + r;
        bf16x4 hv = *(const bf16x4*)(H + (size_t)n * 1024 + tid * 4);
        float hh[4] = {(float)hv[0], (float)hv[1], (float)hv[2], (float)hv[3]};
        bf16x8 sb;
        #pragma unroll
        for (int jj = 0; jj < 8; ++jj) {
            float h0 = hh[(jj >> 2) * 2];
            float h1 = hh[(jj >> 2) * 2 + 1];
            float t = h0 * wv[2 * jj] + h1 * wv[2 * jj + 1] + bb[jj];
            sb[jj] = (bf16)swishf(t);
        }
        *(bf16x8*)&ss[tid * 8] = sb;
        __syncthreads();
        int o8 = tid >> 5, l5 = tid & 31;
        float p = 0.f;
        #pragma unroll
        for (int i = 0; i < 16; ++i) {
            bf16x4 a = *(const bf16x4*)&ss[4 * l5 + 128 * i];
            bf16x4 b = *(const bf16x4*)&sw2[o8][4 * l5 + 128 * i];
            p += (float)a[0] * (float)b[0] + (float)a[1] * (float)b[1]
               + (float)a[2] * (float)b[2] + (float)a[3] * (float)b[3];
        }
        #pragma unroll
        for (int msk = 1; msk < 32; msk <<= 1) p += __shfl_xor(p, msk);
        if (l5 == 0) out[(size_t)n * 8 + o8] = p + b2[o8];
        __syncthreads();
    }
}

// ---------------- launch ----------------

extern "C" void kernel_launch(void* const* d_in, const int* in_sizes, int n_in,
                              void* d_out, int out_size, void* d_ws, size_t ws_size,
                              hipStream_t stream) {
    const float* x     = (const float*)d_in[0];
    const float* codes = (const float*)d_in[1];
    const float* p_w   = (const float*)d_in[2];
    const float* p_b   = (const float*)d_in[3];
    const float* com0  = (const float*)d_in[4];
    const float* code0 = (const float*)d_in[5];
    const float* filt0 = (const float*)d_in[6];
    const float* com1  = (const float*)d_in[7];
    const float* code1 = (const float*)d_in[8];
    const float* filt1 = (const float*)d_in[9];
    const float* w0_w  = (const float*)d_in[10];
    const float* w0_b  = (const float*)d_in[11];
    const float* w1_w  = (const float*)d_in[12];
    const float* w1_b  = (const float*)d_in[13];
    const float* fc1w  = (const float*)d_in[14];
    const float* fc1b  = (const float*)d_in[15];
    const float* fc2w  = (const float*)d_in[16];
    const float* fc2b  = (const float*)d_in[17];
    float* out = (float*)d_out;

    // fixed weight region (~7.1 MB)
    char* ws = (char*)d_ws;
    bf16*  WP   = (bf16*)(ws + 0);               // 1,310,720
    bf16*  B0   = (bf16*)(ws + 1310720);         // 2,359,296
    bf16*  B1   = (bf16*)(ws + 3670016);         // 2,359,296
    bf16*  Fbb  = (bf16*)(ws + 6029312);         // 262,144
    float* Fb32 = (float*)(ws + 6291456);        // 524,288
    float* G32  = (float*)(ws + 6815744);        // 262,144
    float* bias1= (float*)(ws + 7077888);        // 5,120
    float2* cm0 = (float2*)(ws + 7083008);       // 8,192
    float2* cm1 = (float2*)(ws + 7091200);       // 8,192
    const size_t CB = 7099392;

    const size_t PER_ROW = 2048 + 2304 + 2304;   // 6656
    long rmax = 0;
    if (ws_size > CB) rmax = (long)((ws_size - CB) / PER_ROW) / 256 * 256;
    if (rmax > N_ROWS) rmax = N_ROWS;
    if (rmax < 256) {
        hipMemsetAsync(d_out, 0, (size_t)out_size * sizeof(float), stream);
        return;
    }
    const int R = (int)rmax;

    build_cmix<<<4, 256, 0, stream>>>(codes, com0, code0, filt0, cm0);
    build_cmix<<<4, 256, 0, stream>>>(codes, com1, code1, filt1, cm1);
    build_fb2<<<512, 256, 0, stream>>>(Fb32, Fbb);
    build_bcat<<<4608, 256, 0, stream>>>(w0_w, B0);
    build_bcat<<<4608, 256, 0, stream>>>(w1_w, B1);
    build_g<<<dim3(2, 128), 256, 0, stream>>>(Fb32, p_w, G32);
    build_bias1a<<<256, 256, 0, stream>>>(p_w, p_b, bias1);
    build_bias1b<<<32, 256, 0, stream>>>(Fb32, bias1);
    build_wp<<<2560, 256, 0, stream>>>(p_w, G32, WP);

    char* cb = ws + CB;
    for (int row0 = 0; row0 < N_ROWS; row0 += R) {
        const int r = (N_ROWS - row0 < R) ? (N_ROWS - row0) : R;   // multiple of 256
        bf16*  A0  = (bf16*)cb;
        bf16*  H3b = (bf16*)cb;                                    // reuses A0 region
        bf16*  A1  = (bf16*)(cb + (size_t)R * 2048);
        bf16*  A2  = (bf16*)(cb + (size_t)R * 2048 + (size_t)R * 2304);
        const int NX = r / 256;

        convert_x<<<r / 4, 256, 0, stream>>>(x + (size_t)row0 * 512, A0);

        // A1cat[:,0:1024] = A0@p_w[:, :512]^T + bias1; [:,1024:1152] = mix(A0@G^T + b1B)
        gemm256<0, 1><<<NX * 5, 512, 0, stream>>>(
            A0, 512, WP, 512, bias1, A1, 1152, cm0, 1152, 512, NX, 5);
        // A2cat[:,0:1024] = swish(A1cat @ Bcat0^T + w0_b)
        gemm256<1, 0><<<NX * 4, 512, 0, stream>>>(
            A1, 1152, B0, 1152, w0_b, A2, 1152, nullptr, 1024, 1152, NX, 4);
        // A2cat[:,1024:1152] = mix(A2[:,0:1024] @ Fb^T)
        gemm_mix<<<dim3(r / 128, 1), 256, 0, stream>>>(
            A2, 1152, Fbb, 1024, (void*)(A2 + 1024), 1152, cm1, 1024);
        // H3 = A2cat @ Bcat1^T + w1_b (bf16)
        gemm256<0, 0><<<NX * 4, 512, 0, stream>>>(
            A2, 1152, B1, 1152, w1_b, H3b, 1024, nullptr, 1024, 1152, NX, 4);
        // out = fc2(swish(fc1(H3)))
        fc_fused<<<r / 16, 256, 0, stream>>>(H3b, fc1w, fc1b, fc2w, fc2b, out + (size_t)row0 * 8);
    }
}